// Round 9
// baseline (161.780 us; speedup 1.0000x reference)
//
#include <hip/hip_runtime.h>

#define NB 2
#define LQ 256
#define LK 512
#define DM 512
#define NH 8
#define C2F 2.885390081777927f   // 2*log2(e)
#define L2E 1.4426950408889634f

typedef __attribute__((ext_vector_type(8))) short short8;
typedef __attribute__((ext_vector_type(4))) float f32x4;

__device__ __forceinline__ ushort f2bf(float x) {
    unsigned int u = __float_as_uint(x);
    unsigned int r = (u + 0x7fffu + ((u >> 16) & 1u)) >> 16;   // RN-even
    return (ushort)r;
}
__device__ __forceinline__ float bf2f(ushort u) {
    return __uint_as_float(((unsigned int)u) << 16);
}

// ---------------- prep: cvt inputs (blocks 0..1279), cvt+transpose weights
// (blocks 1280..2303), mask compaction (blocks 2304..2305)
__global__ __launch_bounds__(256) void prep_kernel(
    const float* __restrict__ query, const float* __restrict__ key,
    const float* __restrict__ value, const int* __restrict__ mask,
    const float* __restrict__ Wq, const float* __restrict__ Wk,
    const float* __restrict__ Wv, const float* __restrict__ Wo,
    ushort* __restrict__ Ah, ushort* __restrict__ Al,
    ushort* __restrict__ Wth, ushort* __restrict__ Wtl,
    int* __restrict__ vidx, int* __restrict__ nvarr)
{
    __shared__ float T[32][33];
    const int blk = blockIdx.x;
    const int tid = threadIdx.x;

    if (blk < 1280) {
        // ---- cvt inputs: [query;key;value] fp32 -> bf16 hi/lo, rows [2560][512]
        int i = (blk * 256 + tid) * 4;
        const float* src;
        if (i < 262144)       src = query + i;
        else if (i < 786432)  src = key + (i - 262144);
        else                  src = value + (i - 786432);
        float4 x = *reinterpret_cast<const float4*>(src);
        ushort h0 = f2bf(x.x), h1 = f2bf(x.y), h2 = f2bf(x.z), h3 = f2bf(x.w);
        *reinterpret_cast<ushort4*>(&Ah[i]) = make_ushort4(h0, h1, h2, h3);
        *reinterpret_cast<ushort4*>(&Al[i]) = make_ushort4(
            f2bf(x.x - bf2f(h0)), f2bf(x.y - bf2f(h1)),
            f2bf(x.z - bf2f(h2)), f2bf(x.w - bf2f(h3)));
    } else if (blk < 2304) {
        // ---- cvt+transpose weights: W[k][n] fp32 -> Wt[widx][n][k] bf16 hi/lo
        const int bid2 = blk - 1280;
        const int widx = bid2 >> 8;
        const int kt = (bid2 >> 4) & 15, nt = bid2 & 15;
        const float* W = (widx == 0) ? Wq : (widx == 1) ? Wk : (widx == 2) ? Wv : Wo;
        const int rr = tid >> 3, c4 = tid & 7;
        float4 v = *reinterpret_cast<const float4*>(&W[(size_t)(kt * 32 + rr) * 512 + nt * 32 + c4 * 4]);
        T[c4 * 4 + 0][rr] = v.x;
        T[c4 * 4 + 1][rr] = v.y;
        T[c4 * 4 + 2][rr] = v.z;
        T[c4 * 4 + 3][rr] = v.w;
        __syncthreads();
        const int nr = tid >> 3, k4 = tid & 7;
        float x0 = T[nr][k4 * 4 + 0], x1 = T[nr][k4 * 4 + 1];
        float x2 = T[nr][k4 * 4 + 2], x3 = T[nr][k4 * 4 + 3];
        ushort h0 = f2bf(x0), h1 = f2bf(x1), h2 = f2bf(x2), h3 = f2bf(x3);
        size_t o = (size_t)widx * 262144 + (size_t)(nt * 32 + nr) * 512 + kt * 32 + k4 * 4;
        *reinterpret_cast<ushort4*>(&Wth[o]) = make_ushort4(h0, h1, h2, h3);
        *reinterpret_cast<ushort4*>(&Wtl[o]) = make_ushort4(
            f2bf(x0 - bf2f(h0)), f2bf(x1 - bf2f(h1)), f2bf(x2 - bf2f(h2)), f2bf(x3 - bf2f(h3)));
    } else {
        // ---- mask compaction: valid-j index list per batch (1 wave)
        const int b = blk - 2304;
        if (tid < 64) {
            const int lane = tid;
            const int* mb = mask + b * LK;
            int base = 0;
            #pragma unroll
            for (int it = 0; it < 8; ++it) {
                int j = it * 64 + lane;
                bool m = mb[j] != 0;
                unsigned long long bal = __ballot(m);
                int pos = base + (int)__popcll(bal & ((1ull << lane) - 1ull));
                if (m) vidx[b * 512 + pos] = j;
                base += (int)__popcll(bal);
            }
            for (int j = base + lane; j < 512; j += 64) vidx[b * 512 + j] = 0;  // safe pad
            if (lane == 0) nvarr[b] = base;
        }
    }
}

// ---------------- wave-per-16x16-tile split-3 bf16 MFMA GEMM (no LDS, no barriers)
// A[*][512] bf16 hi/lo row-major; Bt[n][k] bf16 hi/lo; C fp32 [*][512] (*scale).
__device__ __forceinline__ void wave_gemm16(
    const ushort* __restrict__ Ah, const ushort* __restrict__ Al, int arow0,
    const ushort* __restrict__ Bth, const ushort* __restrict__ Btl, int ncol0,
    float* __restrict__ C, int crow0, float scale, int lane)
{
    const int fr = lane & 15, k8 = (lane >> 4) * 8;
    const ushort* aph = Ah + (size_t)(arow0 + fr) * 512 + k8;
    const ushort* apl = Al + (size_t)(arow0 + fr) * 512 + k8;
    const ushort* bph = Bth + (size_t)(ncol0 + fr) * 512 + k8;
    const ushort* bpl = Btl + (size_t)(ncol0 + fr) * 512 + k8;
    f32x4 acc = (f32x4)0.0f;
    #pragma unroll 4
    for (int k0 = 0; k0 < 512; k0 += 32) {
        short8 a_h = *reinterpret_cast<const short8*>(aph + k0);
        short8 a_l = *reinterpret_cast<const short8*>(apl + k0);
        short8 b_h = *reinterpret_cast<const short8*>(bph + k0);
        short8 b_l = *reinterpret_cast<const short8*>(bpl + k0);
        acc = __builtin_amdgcn_mfma_f32_16x16x32_bf16(a_h, b_h, acc, 0, 0, 0);
        acc = __builtin_amdgcn_mfma_f32_16x16x32_bf16(a_h, b_l, acc, 0, 0, 0);
        acc = __builtin_amdgcn_mfma_f32_16x16x32_bf16(a_l, b_h, acc, 0, 0, 0);
    }
    // C/D: col = lane&15, row = (lane>>4)*4 + i  [m89-verified]
    #pragma unroll
    for (int i = 0; i < 4; ++i)
        C[(size_t)(crow0 + (lane >> 4) * 4 + i) * 512 + ncol0 + fr] = acc[i] * scale;
}

// qkv: 5120 waves = 1280 blocks. mt 0..159 over [Q;K;V] rows, nt 0..31.
__global__ __launch_bounds__(256) void qkv_gemm_kernel(
    const ushort* __restrict__ Ah, const ushort* __restrict__ Al,
    const ushort* __restrict__ Wth, const ushort* __restrict__ Wtl,
    float* __restrict__ Qb, float* __restrict__ Kb, float* __restrict__ Vb)
{
    const int gw = (blockIdx.x * 256 + threadIdx.x) >> 6;
    const int lane = threadIdx.x & 63;
    const int mt = gw >> 5, nt = gw & 31;
    const ushort* bth; const ushort* btl; float* C; int crow0; float scale;
    if (mt < 32)      { bth = Wth;          btl = Wtl;          C = Qb; crow0 = mt * 16;        scale = C2F; }
    else if (mt < 96) { bth = Wth + 262144; btl = Wtl + 262144; C = Kb; crow0 = (mt - 32) * 16; scale = C2F; }
    else              { bth = Wth + 524288; btl = Wtl + 524288; C = Vb; crow0 = (mt - 96) * 16; scale = 1.0f; }
    wave_gemm16(Ah, Al, mt * 16, bth, btl, nt * 16, C, crow0, scale, lane);
}

// out: 1024 waves = 256 blocks.
__global__ __launch_bounds__(256) void out_gemm_kernel(
    const ushort* __restrict__ xh, const ushort* __restrict__ xl,
    const ushort* __restrict__ Woh, const ushort* __restrict__ Wol,
    float* __restrict__ out)
{
    const int gw = (blockIdx.x * 256 + threadIdx.x) >> 6;
    const int lane = threadIdx.x & 63;
    const int mt = gw >> 5, nt = gw & 31;
    wave_gemm16(xh, xl, mt * 16, Woh, Wol, nt * 16, out, mt * 16, 1.0f, lane);
}

// ---------------- fused additive attention, 2 q-rows/block, grid 2048, compacted j
#define SCOP(QV, KV, WV, U) { \
    float e_ = __builtin_amdgcn_exp2f((QV) + (KV)); \
    float r_ = __builtin_amdgcn_rcpf(1.0f + e_); \
    (U) = fmaf((WV), r_, (U)); }

__global__ __launch_bounds__(256) void attn_kernel(
    const float* __restrict__ Qb, const float* __restrict__ Kb,
    const float* __restrict__ Vb, const float* __restrict__ wa,
    const int* __restrict__ vidx, const int* __restrict__ nvarr,
    ushort* __restrict__ xh, ushort* __restrict__ xl)
{
    __shared__ float qs[2][64];      // Q rows, pre-scaled by C2F in qkv epilogue
    __shared__ float was[64];
    __shared__ float wsm[2][512];    // softmax weights by compact slot
    __shared__ float red[2][8];
    __shared__ float xp[4][2][64];
    __shared__ int vlds[512];
    __shared__ int nv_s;

    const int tid = threadIdx.x;
    const int lane = tid & 63;
    const int w = tid >> 6;
    const int bid = blockIdx.x;          // b*1024 + h*128 + qt
    const int qt = bid & 127;
    const int h = (bid >> 7) & 7;
    const int b = bid >> 10;
    const int q0 = qt * 2;

    if (tid < 128) {
        int r = tid >> 6, d = tid & 63;
        qs[r][d] = Qb[(size_t)(b * LQ + q0 + r) * DM + h * 64 + d];
    }
    if (tid < 64) was[tid] = wa[tid];
    vlds[tid] = vidx[b * 512 + tid];
    vlds[tid + 256] = vidx[b * 512 + tid + 256];
    if (tid == 0) nv_s = nvarr[b];
    __syncthreads();
    const int nv = nv_s;

    // sum of wa (per wave, broadcast to all lanes)
    float swa = was[lane];
    #pragma unroll
    for (int off = 32; off > 0; off >>= 1) swa += __shfl_xor(swa, off);

    const float* Kh = Kb + ((size_t)b * LK) * DM + h * 64;
    float s[2][2];

    // ---- score phase: slot = c*256 + w*64 + lane (balanced under compaction)
    #pragma unroll
    for (int c = 0; c < 2; ++c) {
        const int sbase = c * 256 + w * 64;
        if (sbase >= nv) { s[0][c] = -1e9f; s[1][c] = -1e9f; continue; }
        const int slot = sbase + lane;
        const bool act = slot < nv;
        const int row = vlds[slot];      // padded slots read row 0 (harmless)
        const float* Kp = Kh + (size_t)row * DM;
        float u0 = 0.0f, u1 = 0.0f;
        #pragma unroll
        for (int db = 0; db < 8; ++db) {
            const int d0 = db * 8;
            float4 kA = *reinterpret_cast<const float4*>(&Kp[d0]);
            float4 kB = *reinterpret_cast<const float4*>(&Kp[d0 + 4]);
            float4 qA0 = *reinterpret_cast<const float4*>(&qs[0][d0]);
            float4 qB0 = *reinterpret_cast<const float4*>(&qs[0][d0 + 4]);
            float4 qA1 = *reinterpret_cast<const float4*>(&qs[1][d0]);
            float4 qB1 = *reinterpret_cast<const float4*>(&qs[1][d0 + 4]);
            float4 wA = *reinterpret_cast<const float4*>(&was[d0]);
            float4 wB = *reinterpret_cast<const float4*>(&was[d0 + 4]);
            SCOP(qA0.x, kA.x, wA.x, u0)  SCOP(qA1.x, kA.x, wA.x, u1)
            SCOP(qA0.y, kA.y, wA.y, u0)  SCOP(qA1.y, kA.y, wA.y, u1)
            SCOP(qA0.z, kA.z, wA.z, u0)  SCOP(qA1.z, kA.z, wA.z, u1)
            SCOP(qA0.w, kA.w, wA.w, u0)  SCOP(qA1.w, kA.w, wA.w, u1)
            SCOP(qB0.x, kB.x, wB.x, u0)  SCOP(qB1.x, kB.x, wB.x, u1)
            SCOP(qB0.y, kB.y, wB.y, u0)  SCOP(qB1.y, kB.y, wB.y, u1)
            SCOP(qB0.z, kB.z, wB.z, u0)  SCOP(qB1.z, kB.z, wB.z, u1)
            SCOP(qB0.w, kB.w, wB.w, u0)  SCOP(qB1.w, kB.w, wB.w, u1)
        }
        // score = sum_wa - 2 * sum(wa * rcp(1+e))   (= sum wa*tanh)
        s[0][c] = act ? fmaf(-2.0f, u0, swa) : -1e9f;
        s[1][c] = act ? fmaf(-2.0f, u1, swa) : -1e9f;
    }

    // ---- softmax over compact slots (4 waves x 2 chunks x 64 lanes)
    #pragma unroll
    for (int r = 0; r < 2; ++r) {
        float mx = fmaxf(s[r][0], s[r][1]);
        #pragma unroll
        for (int off = 32; off > 0; off >>= 1) mx = fmaxf(mx, __shfl_xor(mx, off));
        if (lane == 0) red[r][w] = mx;
    }
    __syncthreads();
    float p[2][2];
    #pragma unroll
    for (int r = 0; r < 2; ++r) {
        float gmx = fmaxf(fmaxf(red[r][0], red[r][1]), fmaxf(red[r][2], red[r][3]));
        p[r][0] = __builtin_amdgcn_exp2f((s[r][0] - gmx) * L2E);   // -1e9 -> 0
        p[r][1] = __builtin_amdgcn_exp2f((s[r][1] - gmx) * L2E);
        float sm = p[r][0] + p[r][1];
        #pragma unroll
        for (int off = 32; off > 0; off >>= 1) sm += __shfl_xor(sm, off);
        if (lane == 0) red[r][4 + w] = sm;
    }
    __syncthreads();
    #pragma unroll
    for (int r = 0; r < 2; ++r) {
        float tot = (red[r][4] + red[r][5]) + (red[r][6] + red[r][7]);
        float inv = __builtin_amdgcn_rcpf(tot);
        wsm[r][w * 64 + lane] = p[r][0] * inv;
        wsm[r][256 + w * 64 + lane] = p[r][1] * inv;
    }
    __syncthreads();

    // ---- PV: groups of 4 compact slots, wave-interleaved; lane = d
    const float* Vh = Vb + ((size_t)b * LK) * DM + h * 64;
    float o0 = 0.0f, o1 = 0.0f;
    const int ngr = (nv + 3) >> 2;
    for (int gi = w; gi < ngr; gi += 4) {
        const int sb = gi * 4;
        float4 w0 = *reinterpret_cast<const float4*>(&wsm[0][sb]);
        float4 w1 = *reinterpret_cast<const float4*>(&wsm[1][sb]);
        int j0 = vlds[sb + 0], j1 = vlds[sb + 1], j2 = vlds[sb + 2], j3 = vlds[sb + 3];
        float v0 = Vh[(size_t)j0 * DM + lane];
        float v1 = Vh[(size_t)j1 * DM + lane];
        float v2 = Vh[(size_t)j2 * DM + lane];
        float v3 = Vh[(size_t)j3 * DM + lane];
        o0 = fmaf(w0.x, v0, o0); o0 = fmaf(w0.y, v1, o0);
        o0 = fmaf(w0.z, v2, o0); o0 = fmaf(w0.w, v3, o0);
        o1 = fmaf(w1.x, v0, o1); o1 = fmaf(w1.y, v1, o1);
        o1 = fmaf(w1.z, v2, o1); o1 = fmaf(w1.w, v3, o1);
    }
    xp[w][0][lane] = o0;
    xp[w][1][lane] = o1;
    __syncthreads();
    if (w < 2) {
        const int r = w;
        float acc = (xp[0][r][lane] + xp[1][r][lane]) + (xp[2][r][lane] + xp[3][r][lane]);
        size_t oidx = (size_t)(b * LQ + q0 + r) * DM + h * 64 + lane;
        ushort hb = f2bf(acc);
        xh[oidx] = hb;
        xl[oidx] = f2bf(acc - bf2f(hb));
    }
}

extern "C" void kernel_launch(void* const* d_in, const int* in_sizes, int n_in,
                              void* d_out, int out_size, void* d_ws, size_t ws_size,
                              hipStream_t stream)
{
    const float* query = (const float*)d_in[0];
    const float* key   = (const float*)d_in[1];
    const float* value = (const float*)d_in[2];
    const int*   mask  = (const int*)d_in[3];
    const float* Wq    = (const float*)d_in[4];
    const float* Wk    = (const float*)d_in[5];
    const float* Wv    = (const float*)d_in[6];
    const float* Wo    = (const float*)d_in[7];
    const float* wa    = (const float*)d_in[8];
    float* out = (float*)d_out;

    char* W = (char*)d_ws;
    float*  Qb    = (float*)(W);                        // 512x512 f32   (1 MB), pre-scaled C2F
    float*  Kb    = (float*)(W + 1048576);              // 1024x512 f32  (2 MB), pre-scaled C2F
    float*  Vb    = (float*)(W + 3145728);              // 1024x512 f32  (2 MB)
    ushort* Ah    = (ushort*)(W + 5242880);             // 2560x512 bf16 (2.62 MB)
    ushort* Al    = (ushort*)(W + 7864320);
    ushort* Wth   = (ushort*)(W + 10485760);            // 4x512x512 bf16 (2 MB)
    ushort* Wtl   = (ushort*)(W + 12582912);
    ushort* xh    = (ushort*)(W + 14680064);            // 512x512 bf16 (0.5 MB)
    ushort* xl    = (ushort*)(W + 15204352);
    int*    vidx  = (int*)(W + 15728640);               // 2x512 int
    int*    nvarr = (int*)(W + 15732736);               // 2 int

    prep_kernel<<<dim3(2306), 256, 0, stream>>>(query, key, value, mask,
                                                Wq, Wk, Wv, Wo, Ah, Al, Wth, Wtl, vidx, nvarr);
    qkv_gemm_kernel<<<dim3(1280), 256, 0, stream>>>(Ah, Al, Wth, Wtl, Qb, Kb, Vb);
    attn_kernel<<<dim3(2048), 256, 0, stream>>>(Qb, Kb, Vb, wa, vidx, nvarr, xh, xl);
    out_gemm_kernel<<<dim3(256), 256, 0, stream>>>(xh, xl, Wth + 786432, Wtl + 786432, out);
}

// Round 12
// 136.381 us; speedup vs baseline: 1.1862x; 1.1862x over previous
//
#include <hip/hip_runtime.h>

#define NB 2
#define LQ 256
#define LK 512
#define DM 512
#define NH 8
#define ROWS 4
#define C2F 2.885390081777927f   // 2*log2(e)
#define L2E 1.4426950408889634f

typedef __attribute__((ext_vector_type(8))) short short8;
typedef __attribute__((ext_vector_type(4))) float f32x4;

__device__ __forceinline__ ushort f2bf(float x) {
    unsigned int u = __float_as_uint(x);
    unsigned int r = (u + 0x7fffu + ((u >> 16) & 1u)) >> 16;   // RN-even
    return (ushort)r;
}
__device__ __forceinline__ float bf2f(ushort u) {
    return __uint_as_float(((unsigned int)u) << 16);
}

// ---------------- prep: cvt inputs (blocks 0..1279), cvt+transpose weights
// (blocks 1280..2303), mask compaction -> pinv (blocks 2304..2305)
__global__ __launch_bounds__(256) void prep_kernel(
    const float* __restrict__ query, const float* __restrict__ key,
    const float* __restrict__ value, const int* __restrict__ mask,
    const float* __restrict__ Wq, const float* __restrict__ Wk,
    const float* __restrict__ Wv, const float* __restrict__ Wo,
    ushort* __restrict__ Ah, ushort* __restrict__ Al,
    ushort* __restrict__ Wth, ushort* __restrict__ Wtl,
    int* __restrict__ pinv, int* __restrict__ nvarr)
{
    __shared__ float T[32][33];
    const int blk = blockIdx.x;
    const int tid = threadIdx.x;

    if (blk < 1280) {
        int i = (blk * 256 + tid) * 4;
        const float* src;
        if (i < 262144)       src = query + i;
        else if (i < 786432)  src = key + (i - 262144);
        else                  src = value + (i - 786432);
        float4 x = *reinterpret_cast<const float4*>(src);
        ushort h0 = f2bf(x.x), h1 = f2bf(x.y), h2 = f2bf(x.z), h3 = f2bf(x.w);
        *reinterpret_cast<ushort4*>(&Ah[i]) = make_ushort4(h0, h1, h2, h3);
        *reinterpret_cast<ushort4*>(&Al[i]) = make_ushort4(
            f2bf(x.x - bf2f(h0)), f2bf(x.y - bf2f(h1)),
            f2bf(x.z - bf2f(h2)), f2bf(x.w - bf2f(h3)));
    } else if (blk < 2304) {
        const int bid2 = blk - 1280;
        const int widx = bid2 >> 8;
        const int kt = (bid2 >> 4) & 15, nt = bid2 & 15;
        const float* W = (widx == 0) ? Wq : (widx == 1) ? Wk : (widx == 2) ? Wv : Wo;
        const int rr = tid >> 3, c4 = tid & 7;
        float4 v = *reinterpret_cast<const float4*>(&W[(size_t)(kt * 32 + rr) * 512 + nt * 32 + c4 * 4]);
        T[c4 * 4 + 0][rr] = v.x;
        T[c4 * 4 + 1][rr] = v.y;
        T[c4 * 4 + 2][rr] = v.z;
        T[c4 * 4 + 3][rr] = v.w;
        __syncthreads();
        const int nr = tid >> 3, k4 = tid & 7;
        float x0 = T[nr][k4 * 4 + 0], x1 = T[nr][k4 * 4 + 1];
        float x2 = T[nr][k4 * 4 + 2], x3 = T[nr][k4 * 4 + 3];
        ushort h0 = f2bf(x0), h1 = f2bf(x1), h2 = f2bf(x2), h3 = f2bf(x3);
        size_t o = (size_t)widx * 262144 + (size_t)(nt * 32 + nr) * 512 + kt * 32 + k4 * 4;
        *reinterpret_cast<ushort4*>(&Wth[o]) = make_ushort4(h0, h1, h2, h3);
        *reinterpret_cast<ushort4*>(&Wtl[o]) = make_ushort4(
            f2bf(x0 - bf2f(h0)), f2bf(x1 - bf2f(h1)), f2bf(x2 - bf2f(h2)), f2bf(x3 - bf2f(h3)));
    } else {
        // ---- mask compaction: pinv[j] = compact slot or -1 (1 wave per batch)
        const int b = blk - 2304;
        if (tid < 64) {
            const int lane = tid;
            const int* mb = mask + b * LK;
            int base = 0;
            #pragma unroll
            for (int it = 0; it < 8; ++it) {
                int j = it * 64 + lane;
                bool m = mb[j] != 0;
                unsigned long long bal = __ballot(m);
                int pos = base + (int)__popcll(bal & ((1ull << lane) - 1ull));
                pinv[b * 512 + j] = m ? pos : -1;
                base += (int)__popcll(bal);
            }
            if (lane == 0) nvarr[b] = base;
        }
    }
}

// ---------------- 64x64-tile split-3 bf16 MFMA GEMM main loop (round-6 proven)
__device__ __forceinline__ void gemm64_acc(
    const ushort* __restrict__ Ah, const ushort* __restrict__ Al, int arow0,
    const ushort* __restrict__ Bth, const ushort* __restrict__ Btl, int col0,
    f32x4 (&acc)[2][2])
{
    __shared__ __align__(16) ushort AsH[64 * 40];  // stride 40 ushorts = 80B
    __shared__ __align__(16) ushort AsL[64 * 40];
    __shared__ __align__(16) ushort BsH[64 * 40];
    __shared__ __align__(16) ushort BsL[64 * 40];
    const int tid = threadIdx.x;
    const int lane = tid & 63;
    const int w = tid >> 6, wr = w >> 1, wc = w & 1;
    const int srow = tid >> 2, sk8 = (tid & 3) * 8;

    #pragma unroll
    for (int i = 0; i < 2; ++i)
        #pragma unroll
        for (int j = 0; j < 2; ++j) acc[i][j] = (f32x4)0.0f;

    const int fr_row = (lane & 15), fk8 = (lane >> 4) * 8;

    for (int k0 = 0; k0 < 512; k0 += 32) {
        short8 gah = *reinterpret_cast<const short8*>(&Ah[(size_t)(arow0 + srow) * 512 + k0 + sk8]);
        short8 gal = *reinterpret_cast<const short8*>(&Al[(size_t)(arow0 + srow) * 512 + k0 + sk8]);
        short8 gbh = *reinterpret_cast<const short8*>(&Bth[(size_t)(col0 + srow) * 512 + k0 + sk8]);
        short8 gbl = *reinterpret_cast<const short8*>(&Btl[(size_t)(col0 + srow) * 512 + k0 + sk8]);
        __syncthreads();
        *reinterpret_cast<short8*>(&AsH[srow * 40 + sk8]) = gah;
        *reinterpret_cast<short8*>(&AsL[srow * 40 + sk8]) = gal;
        *reinterpret_cast<short8*>(&BsH[srow * 40 + sk8]) = gbh;
        *reinterpret_cast<short8*>(&BsL[srow * 40 + sk8]) = gbl;
        __syncthreads();
        short8 ah[2], al[2], bh[2], bl[2];
        #pragma unroll
        for (int fr = 0; fr < 2; ++fr) {
            int r = wr * 32 + fr * 16 + fr_row;
            ah[fr] = *reinterpret_cast<const short8*>(&AsH[r * 40 + fk8]);
            al[fr] = *reinterpret_cast<const short8*>(&AsL[r * 40 + fk8]);
        }
        #pragma unroll
        for (int fc = 0; fc < 2; ++fc) {
            int n = wc * 32 + fc * 16 + fr_row;
            bh[fc] = *reinterpret_cast<const short8*>(&BsH[n * 40 + fk8]);
            bl[fc] = *reinterpret_cast<const short8*>(&BsL[n * 40 + fk8]);
        }
        #pragma unroll
        for (int fr = 0; fr < 2; ++fr)
            #pragma unroll
            for (int fc = 0; fc < 2; ++fc) {
                acc[fr][fc] = __builtin_amdgcn_mfma_f32_16x16x32_bf16(ah[fr], bh[fc], acc[fr][fc], 0, 0, 0);
                acc[fr][fc] = __builtin_amdgcn_mfma_f32_16x16x32_bf16(ah[fr], bl[fc], acc[fr][fc], 0, 0, 0);
                acc[fr][fc] = __builtin_amdgcn_mfma_f32_16x16x32_bf16(al[fr], bh[fc], acc[fr][fc], 0, 0, 0);
            }
    }
}

// qkv: 320 blocks; Q stored *C2F; K/V scatter-stored COMPACTED via pinv (K *C2F)
__global__ __launch_bounds__(256) void qkv_gemm_kernel(
    const ushort* __restrict__ Ah, const ushort* __restrict__ Al,
    const ushort* __restrict__ Wth, const ushort* __restrict__ Wtl,
    const int* __restrict__ pinv,
    float* __restrict__ Qb, float* __restrict__ Kc, float* __restrict__ Vc)
{
    const int rb = blockIdx.y, cb = blockIdx.x;
    const int row0 = rb * 64, col0 = cb * 64;
    const ushort* bth; const ushort* btl;
    if (rb < 8)       { bth = Wth;          btl = Wtl; }
    else if (rb < 24) { bth = Wth + 262144; btl = Wtl + 262144; }
    else              { bth = Wth + 524288; btl = Wtl + 524288; }
    f32x4 acc[2][2];
    gemm64_acc(Ah, Al, row0, bth, btl, col0, acc);
    const int lane = threadIdx.x & 63;
    const int w = threadIdx.x >> 6, wr = w >> 1, wc = w & 1;
    // C/D: col = lane&15, row = (lane>>4)*4 + i  [m89-verified]
    #pragma unroll
    for (int fr = 0; fr < 2; ++fr)
        #pragma unroll
        for (int fc = 0; fc < 2; ++fc)
            #pragma unroll
            for (int i = 0; i < 4; ++i) {
                int r = row0 + wr * 32 + fr * 16 + (lane >> 4) * 4 + i;   // 0..2560
                int c = col0 + wc * 32 + fc * 16 + (lane & 15);
                float v = acc[fr][fc][i];
                if (r < 512) {
                    Qb[(size_t)r * 512 + c] = v * C2F;
                } else if (r < 1536) {
                    int rk = r - 512;                     // = b*512 + j
                    int pos = pinv[rk];
                    if (pos >= 0)
                        Kc[(size_t)((rk >> 9) * 512 + pos) * 512 + c] = v * C2F;
                } else {
                    int rv = r - 1536;
                    int pos = pinv[rv];
                    if (pos >= 0)
                        Vc[(size_t)((rv >> 9) * 512 + pos) * 512 + c] = v;
                }
            }
}

// out: 64 blocks, plain store
__global__ __launch_bounds__(256) void out_gemm_kernel(
    const ushort* __restrict__ xh, const ushort* __restrict__ xl,
    const ushort* __restrict__ Woh, const ushort* __restrict__ Wol,
    float* __restrict__ out)
{
    const int row0 = blockIdx.y * 64, col0 = blockIdx.x * 64;
    f32x4 acc[2][2];
    gemm64_acc(xh, xl, row0, Woh, Wol, col0, acc);
    const int lane = threadIdx.x & 63;
    const int w = threadIdx.x >> 6, wr = w >> 1, wc = w & 1;
    #pragma unroll
    for (int fr = 0; fr < 2; ++fr)
        #pragma unroll
        for (int fc = 0; fc < 2; ++fc)
            #pragma unroll
            for (int i = 0; i < 4; ++i) {
                int r = row0 + wr * 32 + fr * 16 + (lane >> 4) * 4 + i;
                int c = col0 + wc * 32 + fc * 16 + (lane & 15);
                out[(size_t)r * 512 + c] = acc[fr][fc][i];
            }
}

// ---------------- fused additive attention, 4 q-rows/block, grid 1024,
// DENSE compacted K/V (slot-indexed, no gather)
#define SCOP(QV, KV, WV, U) { \
    float e_ = __builtin_amdgcn_exp2f((QV) + (KV)); \
    float r_ = __builtin_amdgcn_rcpf(1.0f + e_); \
    (U) = fmaf((WV), r_, (U)); }

__global__ __launch_bounds__(256) void attn_kernel(
    const float* __restrict__ Qb, const float* __restrict__ Kc,
    const float* __restrict__ Vc, const float* __restrict__ wa,
    const int* __restrict__ nvarr,
    ushort* __restrict__ xh, ushort* __restrict__ xl)
{
    __shared__ float qs[ROWS][64];   // pre-scaled C2F (in qkv epilogue)
    __shared__ float was[64];
    __shared__ float wsm[ROWS][512];
    __shared__ float red[ROWS][8];
    __shared__ float xp[4][ROWS][64];
    __shared__ int nv_s;

    const int tid = threadIdx.x;
    const int lane = tid & 63;
    const int w = tid >> 6;
    const int bid = blockIdx.x;          // b*512 + h*64 + qt
    const int qt = bid & 63;
    const int h = (bid >> 6) & 7;
    const int b = bid >> 9;
    const int q0 = qt * ROWS;

    {
        int r = tid >> 6, d = tid & 63;
        qs[r][d] = Qb[(size_t)(b * LQ + q0 + r) * DM + h * 64 + d];
    }
    if (tid < 64) was[tid] = wa[tid];
    if (tid == 0) nv_s = nvarr[b];
    __syncthreads();
    const int nv = nv_s;

    float swa = was[lane];
    #pragma unroll
    for (int off = 32; off > 0; off >>= 1) swa += __shfl_xor(swa, off);

    const float* Kh = Kc + ((size_t)b * LK) * DM + h * 64;
    float s[ROWS][2];

    // ---- score: slot = c*256 + w*64 + lane over dense compact rows
    #pragma unroll
    for (int c = 0; c < 2; ++c) {
        const int sbase = c * 256 + w * 64;
        if (sbase >= nv) {
            #pragma unroll
            for (int r = 0; r < ROWS; ++r) s[r][c] = -1e9f;
            continue;
        }
        const int slot = sbase + lane;
        const bool act = slot < nv;      // pad rows are finite garbage; guarded here
        const float* Kp = Kh + (size_t)slot * DM;
        float u[ROWS] = {0.0f, 0.0f, 0.0f, 0.0f};
        #pragma unroll
        for (int db = 0; db < 8; ++db) {
            const int d0 = db * 8;
            float4 kA = *reinterpret_cast<const float4*>(&Kp[d0]);
            float4 kB = *reinterpret_cast<const float4*>(&Kp[d0 + 4]);
            float4 wA = *reinterpret_cast<const float4*>(&was[d0]);
            float4 wB = *reinterpret_cast<const float4*>(&was[d0 + 4]);
            #pragma unroll
            for (int r = 0; r < ROWS; ++r) {
                float4 qA = *reinterpret_cast<const float4*>(&qs[r][d0]);
                float4 qB = *reinterpret_cast<const float4*>(&qs[r][d0 + 4]);
                SCOP(qA.x, kA.x, wA.x, u[r])
                SCOP(qA.y, kA.y, wA.y, u[r])
                SCOP(qA.z, kA.z, wA.z, u[r])
                SCOP(qA.w, kA.w, wA.w, u[r])
                SCOP(qB.x, kB.x, wB.x, u[r])
                SCOP(qB.y, kB.y, wB.y, u[r])
                SCOP(qB.z, kB.z, wB.z, u[r])
                SCOP(qB.w, kB.w, wB.w, u[r])
            }
        }
        // score = sum_wa - 2 * sum(wa * rcp(1+e))
        #pragma unroll
        for (int r = 0; r < ROWS; ++r)
            s[r][c] = act ? fmaf(-2.0f, u[r], swa) : -1e9f;
    }

    // ---- softmax over compact slots
    #pragma unroll
    for (int r = 0; r < ROWS; ++r) {
        float mx = fmaxf(s[r][0], s[r][1]);
        #pragma unroll
        for (int off = 32; off > 0; off >>= 1) mx = fmaxf(mx, __shfl_xor(mx, off));
        if (lane == 0) red[r][w] = mx;
    }
    __syncthreads();
    float p[ROWS][2];
    #pragma unroll
    for (int r = 0; r < ROWS; ++r) {
        float gmx = fmaxf(fmaxf(red[r][0], red[r][1]), fmaxf(red[r][2], red[r][3]));
        p[r][0] = __builtin_amdgcn_exp2f((s[r][0] - gmx) * L2E);
        p[r][1] = __builtin_amdgcn_exp2f((s[r][1] - gmx) * L2E);
        float sm = p[r][0] + p[r][1];
        #pragma unroll
        for (int off = 32; off > 0; off >>= 1) sm += __shfl_xor(sm, off);
        if (lane == 0) red[r][4 + w] = sm;
    }
    __syncthreads();
    #pragma unroll
    for (int r = 0; r < ROWS; ++r) {
        float tot = (red[r][4] + red[r][5]) + (red[r][6] + red[r][7]);
        float inv = __builtin_amdgcn_rcpf(tot);
        wsm[r][w * 64 + lane] = p[r][0] * inv;
        wsm[r][256 + w * 64 + lane] = p[r][1] * inv;
    }
    __syncthreads();

    // ---- PV: dense compact rows, groups of 4 slots wave-interleaved; lane = d
    const float* Vh = Vc + ((size_t)b * LK) * DM + h * 64;
    float o[ROWS] = {0.0f, 0.0f, 0.0f, 0.0f};
    const int ngr = (nv + 3) >> 2;
    for (int gi = w; gi < ngr; gi += 4) {
        const int sb = gi * 4;
        float4 w0 = *reinterpret_cast<const float4*>(&wsm[0][sb]);
        float4 w1 = *reinterpret_cast<const float4*>(&wsm[1][sb]);
        float4 w2 = *reinterpret_cast<const float4*>(&wsm[2][sb]);
        float4 w3 = *reinterpret_cast<const float4*>(&wsm[3][sb]);
        float v0 = Vh[(size_t)(sb + 0) * DM + lane];
        float v1 = Vh[(size_t)(sb + 1) * DM + lane];
        float v2 = Vh[(size_t)(sb + 2) * DM + lane];
        float v3 = Vh[(size_t)(sb + 3) * DM + lane];
        o[0] = fmaf(w0.x, v0, o[0]); o[0] = fmaf(w0.y, v1, o[0]);
        o[0] = fmaf(w0.z, v2, o[0]); o[0] = fmaf(w0.w, v3, o[0]);
        o[1] = fmaf(w1.x, v0, o[1]); o[1] = fmaf(w1.y, v1, o[1]);
        o[1] = fmaf(w1.z, v2, o[1]); o[1] = fmaf(w1.w, v3, o[1]);
        o[2] = fmaf(w2.x, v0, o[2]); o[2] = fmaf(w2.y, v1, o[2]);
        o[2] = fmaf(w2.z, v2, o[2]); o[2] = fmaf(w2.w, v3, o[2]);
        o[3] = fmaf(w3.x, v0, o[3]); o[3] = fmaf(w3.y, v1, o[3]);
        o[3] = fmaf(w3.z, v2, o[3]); o[3] = fmaf(w3.w, v3, o[3]);
    }
    #pragma unroll
    for (int r = 0; r < ROWS; ++r) xp[w][r][lane] = o[r];
    __syncthreads();
    {
        const int r = w;   // 4 waves, one output row each
        float acc = (xp[0][r][lane] + xp[1][r][lane]) + (xp[2][r][lane] + xp[3][r][lane]);
        size_t oidx = (size_t)(b * LQ + q0 + r) * DM + h * 64 + lane;
        ushort hb = f2bf(acc);
        xh[oidx] = hb;
        xl[oidx] = f2bf(acc - bf2f(hb));
    }
}

extern "C" void kernel_launch(void* const* d_in, const int* in_sizes, int n_in,
                              void* d_out, int out_size, void* d_ws, size_t ws_size,
                              hipStream_t stream)
{
    const float* query = (const float*)d_in[0];
    const float* key   = (const float*)d_in[1];
    const float* value = (const float*)d_in[2];
    const int*   mask  = (const int*)d_in[3];
    const float* Wq    = (const float*)d_in[4];
    const float* Wk    = (const float*)d_in[5];
    const float* Wv    = (const float*)d_in[6];
    const float* Wo    = (const float*)d_in[7];
    const float* wa    = (const float*)d_in[8];
    float* out = (float*)d_out;

    char* W = (char*)d_ws;
    float*  Qb    = (float*)(W);                        // 512x512 f32, *C2F
    float*  Kc    = (float*)(W + 1048576);              // compacted K, *C2F
    float*  Vc    = (float*)(W + 3145728);              // compacted V
    ushort* Ah    = (ushort*)(W + 5242880);             // 2560x512 bf16 hi
    ushort* Al    = (ushort*)(W + 7864320);             // lo
    ushort* Wth   = (ushort*)(W + 10485760);            // 4x[n][k] bf16 hi
    ushort* Wtl   = (ushort*)(W + 12582912);            // lo
    ushort* xh    = (ushort*)(W + 14680064);            // attn out bf16 hi
    ushort* xl    = (ushort*)(W + 15204352);            // lo
    int*    pinv  = (int*)(W + 15728640);               // 2x512 int
    int*    nvarr = (int*)(W + 15732736);               // 2 int

    prep_kernel<<<dim3(2306), 256, 0, stream>>>(query, key, value, mask,
                                                Wq, Wk, Wv, Wo, Ah, Al, Wth, Wtl, pinv, nvarr);
    qkv_gemm_kernel<<<dim3(8, 40), 256, 0, stream>>>(Ah, Al, Wth, Wtl, pinv, Qb, Kc, Vc);
    attn_kernel<<<dim3(1024), 256, 0, stream>>>(Qb, Kc, Vc, wa, nvarr, xh, xl);
    out_gemm_kernel<<<dim3(8, 8), 256, 0, stream>>>(xh, xl, Wth + 786432, Wtl + 786432, out);
}